// Round 4
// baseline (20.707 us; speedup 1.0000x reference)
//
#include <hip/hip_runtime.h>

// out[b] = (x[b] @ Wv + bv) @ Wo + bo   (reference collapses: broadcast over
// seq makes q/k/v seq-constant -> softmax uniform -> attn@v == v; seq-row 0
// of the o-proj is exactly v@Wo+bo). Wq/bq/Wk/bk unused.
//
// Single fused kernel: leg1 -> device-scope grid barrier -> leg2.
// 64 blocks x 256 threads; block owns 16 output cols. Wave reads W as
// 16 rows x 64 B contiguous float4 segments (coalesced). Split-K reduced via
// shfl_xor (barrier-free) + one LDS cross-wave combine.
// Barrier flags zeroed per call by a 256 B hipMemsetAsync (replay/poison safe).

namespace {

constexpr int CD = 1024;  // C
constexpr int BN = 4;     // B
constexpr int NB = 64;    // grid size
constexpr int NC = 16;    // output columns per block

struct SmemT { float xs[BN * CD]; float red[256]; };

// Y[b][i] = sum_c X[b][c] * W[c][i] + bias[i], for i in block's 16-col strip.
__device__ __forceinline__
void leg(const float* __restrict__ Xg, const float* __restrict__ W,
         const float* __restrict__ bias, float* __restrict__ Y, SmemT& sm)
{
    const int tid = threadIdx.x;

    // Stage X (16 KB) into LDS: 4 x 256 threads x float4, coalesced.
    {
        const float4* Xv = (const float4*)Xg;
        float4* xsv = (float4*)sm.xs;
#pragma unroll
        for (int k = 0; k < 4; ++k)
            xsv[k * 256 + tid] = Xv[k * 256 + tid];
    }
    __syncthreads();

    const int cg = tid & 3;          // float4 col-group within strip
    const int ks = tid >> 2;         // k-slice 0..63
    const int colbase = blockIdx.x * NC + cg * 4;

    float a[4][4];                   // [col j in float4][batch b]
#pragma unroll
    for (int j = 0; j < 4; ++j)
#pragma unroll
        for (int b = 0; b < BN; ++b) a[j][b] = 0.f;

    // Rows r = ks + rr*64: per wave-instr, 16 consecutive rows x 64 B
    // contiguous W segments (lanes 0-3 same row, consecutive float4s).
#pragma unroll
    for (int rr = 0; rr < CD / 64; ++rr) {
        const int r = ks + rr * 64;
        const float4 w4 = *(const float4*)(W + (size_t)r * CD + colbase);
        float xb[BN];
#pragma unroll
        for (int b = 0; b < BN; ++b) xb[b] = sm.xs[b * CD + r];  // 16 consec words -> conflict-free broadcast
#pragma unroll
        for (int b = 0; b < BN; ++b) {
            a[0][b] = fmaf(xb[b], w4.x, a[0][b]);
            a[1][b] = fmaf(xb[b], w4.y, a[1][b]);
            a[2][b] = fmaf(xb[b], w4.z, a[2][b]);
            a[3][b] = fmaf(xb[b], w4.w, a[3][b]);
        }
    }

    // Reduce over k-slices within the wave (colgroup = lane&3 preserved).
#pragma unroll
    for (int s = 4; s < 64; s <<= 1)
#pragma unroll
        for (int j = 0; j < 4; ++j)
#pragma unroll
            for (int b = 0; b < BN; ++b)
                a[j][b] += __shfl_xor(a[j][b], s, 64);

    // Cross-wave combine via LDS: red[(wv*4+cg)*16 + j*4 + b].
    const int lane = tid & 63, wv = tid >> 6;
    if (lane < 4) {
#pragma unroll
        for (int j = 0; j < 4; ++j)
#pragma unroll
            for (int b = 0; b < BN; ++b)
                sm.red[(wv * 4 + lane) * 16 + j * 4 + b] = a[j][b];
    }
    __syncthreads();

    // 64 finals: col j2 = tid>>2 (0..15), batch b = tid&3. LDS reads are
    // addr = w*64 + tid -> consecutive, conflict-free.
    if (tid < 64) {
        const int b  = tid & 3;
        const int j2 = tid >> 2;
        const int cg2 = j2 >> 2, j = j2 & 3;
        float s = bias[blockIdx.x * NC + j2];
#pragma unroll
        for (int w = 0; w < 4; ++w)
            s += sm.red[(w * 4 + cg2) * 16 + j * 4 + b];
        Y[b * CD + blockIdx.x * NC + j2] = s;
    }
}

__global__ __launch_bounds__(256, 1)
void fused_two_matvec(const float* __restrict__ x,
                      const float* __restrict__ Wv, const float* __restrict__ bv,
                      const float* __restrict__ Wo, const float* __restrict__ bo,
                      float* __restrict__ t, float* __restrict__ out,
                      int* __restrict__ flags)
{
    __shared__ SmemT sm;

    leg(x, Wv, bv, t, sm);

    // ---- device-scope grid barrier (flags pre-zeroed by memset node) ----
    __syncthreads();                       // all block stores drained (vmcnt(0) at barrier)
    if (threadIdx.x == 0) {
        __threadfence();                   // agent-scope release: t visible past this XCD's L2
        __hip_atomic_store(&flags[blockIdx.x], 1, __ATOMIC_RELEASE,
                           __HIP_MEMORY_SCOPE_AGENT);
    }
    if (threadIdx.x < NB) {
        while (__hip_atomic_load(&flags[threadIdx.x], __ATOMIC_ACQUIRE,
                                 __HIP_MEMORY_SCOPE_AGENT) == 0)
            __builtin_amdgcn_s_sleep(2);
    }
    __syncthreads();
    // ---------------------------------------------------------------------

    leg(t, Wo, bo, out, sm);
}

} // namespace

extern "C" void kernel_launch(void* const* d_in, const int* in_sizes, int n_in,
                              void* d_out, int out_size, void* d_ws, size_t ws_size,
                              hipStream_t stream)
{
    // setup_inputs() order: x, Wq, bq, Wk, bk, Wv, bv, Wo, bo  (all fp32)
    const float* x  = (const float*)d_in[0];
    const float* Wv = (const float*)d_in[5];
    const float* bv = (const float*)d_in[6];
    const float* Wo = (const float*)d_in[7];
    const float* bo = (const float*)d_in[8];
    float* out = (float*)d_out;

    int*   flags = (int*)d_ws;                 // 64 ints, zeroed every call
    float* t     = (float*)d_ws + 1024;        // [4][1024] intermediate (4 KB offset)

    hipMemsetAsync(d_ws, 0, NB * sizeof(int), stream);
    fused_two_matvec<<<NB, 256, 0, stream>>>(x, Wv, bv, Wo, bo, t, out, flags);
}